// Round 24
// baseline (399.810 us; speedup 1.0000x reference)
//
#include <hip/hip_runtime.h>
#include <hip/hip_bf16.h>

// FFT-tiled conv: B=8, IMG=256, CIN=COUT=64, TILE=64, FFT=68, PAD=2.
// Frequency-domain per-tile conv via DFT-as-matmul, Hermitian half-spectrum
// (k2 in [0,35)), direct overlap-add (plain stores interior, atomics on seams,
// seam bands pre-zeroed). ALL five stages run on bf16 MFMA.
// ALL intermediates (Y,X,O,Z) stored as packed bf16 complex (uint re|im<<16).
//
// Layouts (per 16-tile chunk slot of CHS uints, oversized):
//   Y  [nl][k2][r][i]    uint   ((nl*35+k2)*64+r)*64 + i
//   X  [nl][k1][k2][i]   uint   ((nl*68+k1)*35+k2)*64 + i
//   O  [nl][k2][k1][o]   uint   ((nl*35+k2)*68+k1)*64 + o
//   Z  [nl][p][k2][o]    uint   ((nl*68+p)*35+k2)*64 + o
//   Ktb[bin][2][o][i] bf16 pre-swizzled, 39 MB one-time (bin = k1*35+k2)
//
// Twiddle tables:
//   Wfb [2][80][64] bf16 rows>=68 zero              (5120 floats)
//   Wib [2][80][128] bf16 pre-swizzled, zero-pad    (10240 floats)
//   Wgb [80][128] bf16 pre-swizzled, K=[Wgr|-Wgi]   (5120 floats)

#define KH   35
#define CHS  4874240ull                       // elements per chunk slot
#define KTB_FLOATS 9748480ull
#define WS_HEAD 34456ull

typedef float f32x4 __attribute__((ext_vector_type(4)));
typedef short s16x8 __attribute__((ext_vector_type(8)));

__device__ __forceinline__ ushort f2bf(float f) {
    __hip_bfloat16 h = __float2bfloat16(f);
    return *reinterpret_cast<ushort*>(&h);
}
__device__ __forceinline__ uint pkbf(float re, float im) {
    return (uint)f2bf(re) | ((uint)f2bf(im) << 16);
}

__global__ void k_twiddle(float* ws) {
    const float TWO_PI = 6.28318530717958647692f;
    int t = threadIdx.x;
    ushort* Wfb = (ushort*)(ws + 13976);  // [2][80][64] bf16
    for (int e = t; e < 80 * 64; e += 256) {
        int k = e >> 6, r = e & 63;
        float vr = 0.f, vi = 0.f;
        if (k < 68) {
            int ph = (k * (r + 2)) % 68;
            float a = TWO_PI * (float)ph / 68.0f;
            vr = cosf(a); vi = -sinf(a);
        }
        Wfb[e]        = f2bf(vr);
        Wfb[5120 + e] = f2bf(vi);
    }
    ushort* Wib = (ushort*)(ws + 19096);  // [2][80][128] bf16 pre-swizzled
    for (int e = t; e < 80 * 96; e += 256) {
        int p = e / 96, k = e % 96;
        float vr = 0.f, vi = 0.f;
        if (p < 68 && k < 68) {
            int ph = (p * k) % 68;
            float a = TWO_PI * (float)ph / 68.0f;
            vr = cosf(a) / 68.0f; vi = sinf(a) / 68.0f;
        }
        int dst = p * 128 + (((k >> 3) ^ (p & 7)) << 3) + (k & 7);
        Wib[dst]         = f2bf(vr);
        Wib[10240 + dst] = f2bf(vi);
    }
    ushort* Wgb = (ushort*)(ws + 29336);  // [80][128] bf16 pre-swizzled
    for (int e = t; e < 80 * 96; e += 256) {
        int q = e / 96, k = e % 96;
        float v = 0.f;
        if (q < 68 && k < 70) {
            int k2 = (k < KH) ? k : (k - KH);
            int ph = (q * k2) % 68;
            float a = TWO_PI * (float)ph / 68.0f;
            float alpha = (k2 == 0 || k2 == 34) ? 1.0f : 2.0f;
            v = (k < KH) ? (alpha * cosf(a) / 68.0f)
                         : (-alpha * sinf(a) / 68.0f);
        }
        int dst = q * 128 + (((k >> 3) ^ (q & 7)) << 3) + (k & 7);
        Wgb[dst] = f2bf(v);
    }
}

// zero only the seam bands (rows/cols 66,67,132,133,198,199 of each image)
__global__ void k_zero_seams(float* out) {
    int b = blockIdx.x / 12, line = blockIdx.x % 12;
    const int seam[6] = {66, 67, 132, 133, 198, 199};
    int t = threadIdx.x;
    if (line < 6) {
        int y = seam[line];
        float4* dst = (float4*)(out + ((size_t)(b * 256 + y)) * 256 * 64);
        for (int e = t; e < 4096; e += 256) dst[e] = make_float4(0, 0, 0, 0);
    } else {
        int x = seam[line - 6];
        float4* dst = (float4*)out;
        for (int e = t; e < 4096; e += 256) {
            int y = e >> 4, f = e & 15;
            dst[(((size_t)(b * 256 + y)) * 256 + x) * 16 + f] = make_float4(0, 0, 0, 0);
        }
    }
}

// ---------- one-time: kernel spectrum -> Ktb bf16 [bin][plane][o][i_swz] ----
// Block = (k1-quad, o). Rows tile exactly into 17 windows of 272 floats:
// stage 64 rows x 272 floats fully coalesced, two phases (re/im) reusing one
// 69.6 KB buffer; writes emit full 128 B swizzled Ktb rows.
__global__ __launch_bounds__(256) void k_kprep(
        const float* __restrict__ kr, const float* __restrict__ ki,
        ushort* __restrict__ Ktb) {
    __shared__ float sW[64 * 272];      // 69.6 KB
    int k1q = blockIdx.x >> 6, o = blockIdx.x & 63;
    int t = threadIdx.x;
    for (int ph = 0; ph < 2; ++ph) {
        const float* src = ph ? ki : kr;
        for (int e = t; e < 64 * 68; e += 256) {
            int ii = e / 68, f = e % 68;
            size_t g = ((size_t)(o * 64 + ii) * 68 + k1q * 4) * 68 + f * 4;
            *(float4*)&sW[ii * 272 + f * 4] = *(const float4*)(src + g);
        }
        __syncthreads();
        for (int e = t; e < 4 * KH * 64; e += 256) {
            int k1l = e / 2240;
            int rem = e % 2240;
            int k2 = rem >> 6, i = rem & 63;
            int sw = (((i >> 3) ^ (o & 7)) << 3) | (i & 7);
            size_t dst = ((size_t)((4 * k1q + k1l) * KH + k2)) * 8192
                         + (size_t)ph * 4096 + (size_t)o * 64 + sw;
            Ktb[dst] = f2bf(sW[i * 272 + k1l * 68 + k2]);
        }
        __syncthreads();
    }
}

// ---------------- stage 1: row DFT — bf16 MFMA ----------------
// Y[nl][k2][r][i] = sum_c x[b, tr*64+r, tc*64+c, i] * Wf[k2][c]
__global__ __launch_bounds__(512) void k_fwd_row(
        const float* __restrict__ x, const ushort* __restrict__ Wfb,
        uint* __restrict__ Y, int c0) {
    __shared__ __align__(16) ushort sAr[48 * 64];
    __shared__ __align__(16) ushort sAi[48 * 64];
    __shared__ __align__(16) ushort sB[4 * 64 * 64];
    int gid = blockIdx.x;
    int lc = gid >> 8;
    int rem = gid & 255;
    int nl = rem >> 4, rq = rem & 15;
    int n = (c0 + lc) * 16 + nl;
    int b = n >> 4, tr = (n >> 2) & 3, tc = n & 3;
    int t = threadIdx.x;
    for (int e = t; e < 3072; e += 512) {
        int m = e >> 6, c = e & 63;
        int sw = (m << 6) + (((c >> 3) ^ (m & 7)) << 3) + (c & 7);
        sAr[sw] = Wfb[e];
        sAi[sw] = Wfb[5120 + e];
    }
    for (int e = t; e < 4096; e += 512) {
        int rr = e >> 10, f = e & 1023;
        int c = f >> 4, i0 = (f & 15) << 2;
        int y = tr * 64 + rq * 4 + rr;
        const float4* src = (const float4*)(x + ((size_t)(b * 256 + y) * 256
                                                 + tc * 64) * 64 + (c << 6) + i0);
        float4 v = *src;
        float vv[4] = {v.x, v.y, v.z, v.w};
        #pragma unroll
        for (int u = 0; u < 4; ++u) {
            int i = i0 + u;
            sB[(rr << 12) + (i << 6) + (((c >> 3) ^ (i & 7)) << 3) + (c & 7)]
                = f2bf(vv[u]);
        }
    }
    __syncthreads();
    uint* Yc = Y + (size_t)lc * CHS;
    int lane = t & 63, w = t >> 6;
    int lm = lane & 15, kg = lane >> 4;
    int ba0 = ((kg ^ (lm & 7)) << 3);
    int ba1 = (((kg + 4) ^ (lm & 7)) << 3);
    for (int tid = w; tid < 48; tid += 8) {
        int rr = tid / 12, rem2 = tid % 12;
        int mt = rem2 >> 2, nt = rem2 & 3;
        int am = mt * 16 + lm, bn = nt * 16 + lm;
        s16x8 a0r = *(const s16x8*)(sAr + (am << 6) + ba0);
        s16x8 a1r = *(const s16x8*)(sAr + (am << 6) + ba1);
        s16x8 a0i = *(const s16x8*)(sAi + (am << 6) + ba0);
        s16x8 a1i = *(const s16x8*)(sAi + (am << 6) + ba1);
        s16x8 b0 = *(const s16x8*)(sB + (rr << 12) + (bn << 6) + ba0);
        s16x8 b1 = *(const s16x8*)(sB + (rr << 12) + (bn << 6) + ba1);
        f32x4 yr = {0.f, 0.f, 0.f, 0.f}, yi = yr;
        yr = __builtin_amdgcn_mfma_f32_16x16x32_bf16(a0r, b0, yr, 0, 0, 0);
        yr = __builtin_amdgcn_mfma_f32_16x16x32_bf16(a1r, b1, yr, 0, 0, 0);
        yi = __builtin_amdgcn_mfma_f32_16x16x32_bf16(a0i, b0, yi, 0, 0, 0);
        yi = __builtin_amdgcn_mfma_f32_16x16x32_bf16(a1i, b1, yi, 0, 0, 0);
        int r = rq * 4 + rr;
        #pragma unroll
        for (int g2 = 0; g2 < 4; ++g2) {
            int k2 = mt * 16 + kg * 4 + g2;
            if (k2 < KH)
                Yc[((size_t)(nl * KH + k2) * 64 + r) * 64 + nt * 16 + lm]
                    = pkbf(yr[g2], yi[g2]);
        }
    }
}

// ---------------- stage 2: column DFT — bf16 MFMA ----------------
// X[nl][k1][k2][i] = sum_r Wf[k1][r] * Y[nl][k2][r][i]
__global__ __launch_bounds__(512) void k_fwd_col(
        const uint* __restrict__ Y, const ushort* __restrict__ Wfb,
        uint* __restrict__ X) {
    __shared__ __align__(16) ushort sAr[80 * 64];
    __shared__ __align__(16) ushort sAi[80 * 64];
    __shared__ __align__(16) ushort sBr[64 * 64];
    __shared__ __align__(16) ushort sBi[64 * 64];
    int lc = blockIdx.x / 560;
    int rem = blockIdx.x % 560;
    int nl = rem / KH, k2 = rem % KH;
    const uint* Yg = Y + (size_t)lc * CHS + ((size_t)(nl * KH + k2)) * 4096;
    uint* Xc = X + (size_t)lc * CHS;
    int t = threadIdx.x;
    for (int e = t; e < 5120; e += 512) {
        int m = e >> 6, r = e & 63;
        int sw = (m << 6) + ((((r >> 3) ^ (m & 7))) << 3) + (r & 7);
        sAr[sw] = Wfb[e];
        sAi[sw] = Wfb[5120 + e];
    }
    for (int e = t; e < 4096; e += 512) {
        int i = e & 63, r = e >> 6;
        uint v = Yg[e];
        int sw = (i << 6) + ((((r >> 3) ^ (i & 7))) << 3) + (r & 7);
        sBr[sw] = (ushort)(v & 0xffff);
        sBi[sw] = (ushort)(v >> 16);
    }
    __syncthreads();
    int lane = t & 63, w = t >> 6;
    int lm = lane & 15, kg = lane >> 4;
    int ba0 = ((kg ^ (lm & 7)) << 3);
    int ba1 = (((kg + 4) ^ (lm & 7)) << 3);
    for (int tid = w; tid < 20; tid += 8) {
        int mt = tid >> 2, nt = tid & 3;
        int am = mt * 16 + lm, bn = nt * 16 + lm;
        s16x8 ar0 = *(const s16x8*)(sAr + (am << 6) + ba0);
        s16x8 ar1 = *(const s16x8*)(sAr + (am << 6) + ba1);
        s16x8 ai0 = *(const s16x8*)(sAi + (am << 6) + ba0);
        s16x8 ai1 = *(const s16x8*)(sAi + (am << 6) + ba1);
        s16x8 br0 = *(const s16x8*)(sBr + (bn << 6) + ba0);
        s16x8 br1 = *(const s16x8*)(sBr + (bn << 6) + ba1);
        s16x8 bi0 = *(const s16x8*)(sBi + (bn << 6) + ba0);
        s16x8 bi1 = *(const s16x8*)(sBi + (bn << 6) + ba1);
        f32x4 rr = {0.f, 0.f, 0.f, 0.f}, ii = rr, ri = rr, ir = rr;
        rr = __builtin_amdgcn_mfma_f32_16x16x32_bf16(ar0, br0, rr, 0, 0, 0);
        rr = __builtin_amdgcn_mfma_f32_16x16x32_bf16(ar1, br1, rr, 0, 0, 0);
        ii = __builtin_amdgcn_mfma_f32_16x16x32_bf16(ai0, bi0, ii, 0, 0, 0);
        ii = __builtin_amdgcn_mfma_f32_16x16x32_bf16(ai1, bi1, ii, 0, 0, 0);
        ri = __builtin_amdgcn_mfma_f32_16x16x32_bf16(ar0, bi0, ri, 0, 0, 0);
        ri = __builtin_amdgcn_mfma_f32_16x16x32_bf16(ar1, bi1, ri, 0, 0, 0);
        ir = __builtin_amdgcn_mfma_f32_16x16x32_bf16(ai0, br0, ir, 0, 0, 0);
        ir = __builtin_amdgcn_mfma_f32_16x16x32_bf16(ai1, br1, ir, 0, 0, 0);
        #pragma unroll
        for (int g2 = 0; g2 < 4; ++g2) {
            int k1 = mt * 16 + kg * 4 + g2;
            if (k1 < 68)
                Xc[((size_t)(nl * 68 + k1) * KH + k2) * 64 + nt * 16 + lm]
                    = pkbf(rr[g2] - ii[g2], ri[g2] + ir[g2]);
        }
    }
}

// ---------------- stage 3: channel mix — bf16 MFMA ----------------
// O[nl][k2][k1][o] = sum_i X[nl][k1][k2][i] * K[bin][i][o]
// Block = bin; Ktb staged ONCE in LDS, loop over all CH chunks.
__global__ __launch_bounds__(256) void k_mix(
        const uint* __restrict__ X, const ushort* __restrict__ Ktb,
        uint* __restrict__ O, int CH) {
    __shared__ __align__(16) ushort sAr[16 * 64];
    __shared__ __align__(16) ushort sAi[16 * 64];
    __shared__ __align__(16) ushort sB[2 * 64 * 64];
    int bin = blockIdx.x;
    int k1 = bin / KH, k2 = bin % KH;
    int t = threadIdx.x;
    const uint4* ksrc = (const uint4*)(Ktb + (size_t)bin * 8192);
    for (int e = t; e < 1024; e += 256) ((uint4*)sB)[e] = ksrc[e];
    const ushort* sBr = sB;
    const ushort* sBi = sB + 4096;
    int lane = t & 63, w = t >> 6;
    int lm = lane & 15, kg = lane >> 4;
    for (int lc = 0; lc < CH; ++lc) {
        const uint* Xc = X + (size_t)lc * CHS;
        uint* Oc = O + (size_t)lc * CHS;
        for (int e = t; e < 1024; e += 256) {
            int n = e >> 6, i = e & 63;
            uint v = Xc[((size_t)(n * 68 + k1) * KH + k2) * 64 + i];
            int sw = (n << 6) + (((i >> 3) ^ (n & 7)) << 3) + (i & 7);
            sAr[sw] = (ushort)(v & 0xffff);
            sAi[sw] = (ushort)(v >> 16);
        }
        __syncthreads();
        f32x4 rr = {0.f, 0.f, 0.f, 0.f}, ii = rr, ri = rr, ir = rr;
        #pragma unroll
        for (int st = 0; st < 2; ++st) {
            int blk = kg + st * 4;
            int ao = (lm << 6) + ((blk ^ (lm & 7)) << 3);
            int bo = ((w * 16 + lm) << 6) + ((blk ^ (lm & 7)) << 3);
            s16x8 axr = *(const s16x8*)(sAr + ao);
            s16x8 axi = *(const s16x8*)(sAi + ao);
            s16x8 bxr = *(const s16x8*)(sBr + bo);
            s16x8 bxi = *(const s16x8*)(sBi + bo);
            rr = __builtin_amdgcn_mfma_f32_16x16x32_bf16(axr, bxr, rr, 0, 0, 0);
            ii = __builtin_amdgcn_mfma_f32_16x16x32_bf16(axi, bxi, ii, 0, 0, 0);
            ri = __builtin_amdgcn_mfma_f32_16x16x32_bf16(axr, bxi, ri, 0, 0, 0);
            ir = __builtin_amdgcn_mfma_f32_16x16x32_bf16(axi, bxr, ir, 0, 0, 0);
        }
        #pragma unroll
        for (int g2 = 0; g2 < 4; ++g2) {
            int n = kg * 4 + g2;
            int o = w * 16 + lm;
            Oc[(((size_t)n * KH + k2) * 68 + k1) * 64 + o]
                = pkbf(rr[g2] - ii[g2], ri[g2] + ir[g2]);
        }
        __syncthreads();
    }
}

// ---------------- stage 4: inverse column DFT — bf16 MFMA ----------------
// Z[nl][p][k2][o] = sum_k1 Wi[p][k1] * O[nl][k2][k1][o]
__global__ __launch_bounds__(512) void k_inv_col(
        const uint* __restrict__ O, const ushort* __restrict__ Wib,
        uint* __restrict__ Z) {
    __shared__ __align__(16) ushort sAr[80 * 128];
    __shared__ __align__(16) ushort sAi[80 * 128];
    __shared__ __align__(16) ushort sBr[64 * 128];
    __shared__ __align__(16) ushort sBi[64 * 128];
    int lc = blockIdx.x / 560;
    int rem = blockIdx.x % 560;
    int nl = rem / KH, k2 = rem % KH;
    int t = threadIdx.x;
    const uint* Ob = O + (size_t)lc * CHS + ((size_t)nl * KH + k2) * 68 * 64;
    uint* Zc = Z + (size_t)lc * CHS;
    const uint4* wsrc = (const uint4*)Wib;
    for (int e = t; e < 1280; e += 512) ((uint4*)sAr)[e] = wsrc[e];
    for (int e = t; e < 1280; e += 512) ((uint4*)sAi)[e] = wsrc[1280 + e];
    uint4 zz = {0, 0, 0, 0};
    for (int e = t; e < 1024; e += 512) { ((uint4*)sBr)[e] = zz; ((uint4*)sBi)[e] = zz; }
    __syncthreads();
    for (int e = t; e < 4352; e += 512) {
        int k1 = e >> 6, o = e & 63;
        uint v = Ob[e];
        int sw = o * 128 + (((k1 >> 3) ^ (o & 7)) << 3) + (k1 & 7);
        sBr[sw] = (ushort)(v & 0xffff);
        sBi[sw] = (ushort)(v >> 16);
    }
    __syncthreads();
    int lane = t & 63, w = t >> 6;
    int lm = lane & 15, kg = lane >> 4;
    for (int tid = w; tid < 20; tid += 8) {
        int mt = tid >> 2, nt = tid & 3;
        int am = mt * 16 + lm, bn = nt * 16 + lm;
        f32x4 rr = {0.f, 0.f, 0.f, 0.f}, ii = rr, ri = rr, ir = rr;
        #pragma unroll
        for (int st = 0; st < 3; ++st) {
            int blk = kg + st * 4;
            int off = ((blk ^ (lm & 7)) << 3);
            s16x8 axr = *(const s16x8*)(sAr + am * 128 + off);
            s16x8 axi = *(const s16x8*)(sAi + am * 128 + off);
            s16x8 bxr = *(const s16x8*)(sBr + bn * 128 + off);
            s16x8 bxi = *(const s16x8*)(sBi + bn * 128 + off);
            rr = __builtin_amdgcn_mfma_f32_16x16x32_bf16(axr, bxr, rr, 0, 0, 0);
            ii = __builtin_amdgcn_mfma_f32_16x16x32_bf16(axi, bxi, ii, 0, 0, 0);
            ri = __builtin_amdgcn_mfma_f32_16x16x32_bf16(axr, bxi, ri, 0, 0, 0);
            ir = __builtin_amdgcn_mfma_f32_16x16x32_bf16(axi, bxr, ir, 0, 0, 0);
        }
        #pragma unroll
        for (int g2 = 0; g2 < 4; ++g2) {
            int p = mt * 16 + kg * 4 + g2;
            if (p < 68)
                Zc[(((size_t)(nl * 68 + p)) * KH + k2) * 64 + nt * 16 + lm]
                    = pkbf(rr[g2] - ii[g2], ri[g2] + ir[g2]);
        }
    }
}

// ---------------- stage 5: inverse row DFT + overlap-add — bf16 MFMA --------
// Block = (lc, nl, p-quad): Wgb staged once, 4 p-rows, double-buffered B.
__global__ __launch_bounds__(512) void k_fused_inv(
        const uint* __restrict__ Z, const ushort* __restrict__ Wgb,
        const float* __restrict__ bias, float* __restrict__ out, int c0) {
    __shared__ __align__(16) ushort sWg[80 * 128];      // 20 KB
    __shared__ __align__(16) ushort sBq[2][64 * 128];   // 32 KB
    int bid = blockIdx.x;
    int lc = bid / 272;
    int rem = bid % 272;
    int nl = rem / 17, pq = rem % 17;
    int b = c0 + lc;
    int tr = nl >> 2, tc = nl & 3;
    int t = threadIdx.x;
    const uint4* wsrc = (const uint4*)Wgb;
    for (int e = t; e < 1280; e += 512) ((uint4*)sWg)[e] = wsrc[e];
    uint4 zz = {0, 0, 0, 0};
    for (int e = t; e < 2048; e += 512) ((uint4*)sBq[0])[e] = zz;  // both bufs
    int lane = t & 63, w = t >> 6;
    int lm = lane & 15, kg = lane >> 4;
    float bv4[4];
    #pragma unroll
    for (int nt = 0; nt < 4; ++nt) bv4[nt] = bias[nt * 16 + lm];
    __syncthreads();
    for (int pp = 0; pp < 4; ++pp) {
        int p = pq * 4 + pp;
        int y = 66 * tr + p;
        if (y >= 256) break;            // block-uniform
        ushort* Bq = sBq[pp & 1];
        const uint* Zb = Z + (size_t)lc * CHS + ((size_t)(nl * 68 + p)) * KH * 64;
        for (int e = t; e < KH * 64; e += 512) {
            int k2 = e >> 6, o = e & 63;
            uint v = Zb[e];
            int kb = k2 + KH;
            Bq[o * 128 + (((k2 >> 3) ^ (o & 7)) << 3) + (k2 & 7)] = (ushort)(v & 0xffff);
            Bq[o * 128 + (((kb >> 3) ^ (o & 7)) << 3) + (kb & 7)] = (ushort)(v >> 16);
        }
        __syncthreads();
        bool rowu = !((p <= 1 && tr > 0) || (p >= 66 && tr < 3));
        float* orow = out + ((size_t)(b * 256 + y)) * 256 * 64;
        for (int tid = w; tid < 20; tid += 8) {
            int mt = tid >> 2, nt = tid & 3;
            int am = mt * 16 + lm, bn = nt * 16 + lm;
            f32x4 acc = {0.f, 0.f, 0.f, 0.f};
            #pragma unroll
            for (int st = 0; st < 3; ++st) {
                int blk = kg + st * 4;
                int off = ((blk ^ (lm & 7)) << 3);
                s16x8 av = *(const s16x8*)(sWg + am * 128 + off);
                s16x8 bv = *(const s16x8*)(Bq + bn * 128 + off);
                acc = __builtin_amdgcn_mfma_f32_16x16x32_bf16(av, bv, acc, 0, 0, 0);
            }
            int o = nt * 16 + lm;
            #pragma unroll
            for (int g2 = 0; g2 < 4; ++g2) {
                int q = mt * 16 + kg * 4 + g2;
                if (q >= 68) continue;
                int xx = 66 * tc + q;
                if (xx >= 256) continue;
                bool colu = !((q <= 1 && tc > 0) || (q >= 66 && tc < 3));
                float v = acc[g2] + bv4[nt];
                float* addr = orow + (size_t)xx * 64 + o;
                if (rowu && colu) *addr = v;
                else              atomicAdd(addr, v);
            }
        }
    }
}

extern "C" void kernel_launch(void* const* d_in, const int* in_sizes, int n_in,
                              void* d_out, int out_size, void* d_ws, size_t ws_size,
                              hipStream_t stream) {
    const float* x    = (const float*)d_in[0];
    const float* kr   = (const float*)d_in[1];
    const float* ki   = (const float*)d_in[2];
    const float* bias = (const float*)d_in[3];
    float* out = (float*)d_out;
    float* ws  = (float*)d_ws;

    int CH = 8;
    while (CH > 4 && (WS_HEAD + KTB_FLOATS + 2ull * CH * CHS) * 4ull > ws_size)
        CH >>= 1;

    ushort* Wfb  = (ushort*)(ws + 13976);
    ushort* Wib  = (ushort*)(ws + 19096);
    ushort* Wgb  = (ushort*)(ws + 29336);
    ushort* Ktb  = (ushort*)(ws + WS_HEAD);
    float*  bufA = ws + WS_HEAD + KTB_FLOATS;  // Y then O (as uint)
    float*  bufB = bufA + (size_t)CH * CHS;    // X then Z

    k_twiddle<<<1, 256, 0, stream>>>(ws);
    k_kprep<<<17 * 64, 256, 0, stream>>>(kr, ki, Ktb);
    k_zero_seams<<<96, 256, 0, stream>>>(out);

    for (int s = 0; s < 8; s += CH) {
        k_fwd_row<<<CH * 256, 512, 0, stream>>>(x, Wfb, (uint*)bufA, s);
        k_fwd_col<<<CH * 560, 512, 0, stream>>>((const uint*)bufA, Wfb, (uint*)bufB);
        k_mix<<<2380, 256, 0, stream>>>((const uint*)bufB, Ktb, (uint*)bufA, CH);
        k_inv_col<<<CH * 560, 512, 0, stream>>>((const uint*)bufA, Wib, (uint*)bufB);
        k_fused_inv<<<CH * 272, 512, 0, stream>>>((const uint*)bufB, Wgb, bias, out, s);
    }
}

// Round 25
// 371.954 us; speedup vs baseline: 1.0749x; 1.0749x over previous
//
#include <hip/hip_runtime.h>
#include <hip/hip_bf16.h>

// FFT-tiled conv: B=8, IMG=256, CIN=COUT=64, TILE=64, FFT=68, PAD=2.
// Frequency-domain per-tile conv via DFT-as-matmul, Hermitian half-spectrum
// (k2 in [0,35)), direct overlap-add (plain stores interior, atomics on seams,
// seam bands pre-zeroed). ALL five stages run on bf16 MFMA.
// ALL intermediates (Y,X,O,Z) stored as packed bf16 complex (uint re|im<<16).
//
// Layouts (per 16-tile chunk slot of CHS uints, oversized):
//   Y  [nl][k2][r][i]    uint   ((nl*35+k2)*64+r)*64 + i
//   X  [nl][k1][k2][i]   uint   ((nl*68+k1)*35+k2)*64 + i
//   O  [nl][k2][k1][o]   uint   ((nl*35+k2)*68+k1)*64 + o
//   Z  [nl][p][k2][o]    uint   ((nl*68+p)*35+k2)*64 + o
//   Ktb[bin][2][o][i] bf16 pre-swizzled, 39 MB one-time (bin = k1*35+k2)
//
// Twiddle tables:
//   Wfb [2][80][64] bf16 rows>=68 zero              (5120 floats)
//   Wib [2][80][128] bf16 pre-swizzled, zero-pad    (10240 floats)
//   Wgb [80][128] bf16 pre-swizzled, K=[Wgr|-Wgi]   (5120 floats)

#define KH   35
#define CHS  4874240ull                       // elements per chunk slot
#define KTB_FLOATS 9748480ull
#define WS_HEAD 34456ull

typedef float f32x4 __attribute__((ext_vector_type(4)));
typedef short s16x8 __attribute__((ext_vector_type(8)));

__device__ __forceinline__ ushort f2bf(float f) {
    __hip_bfloat16 h = __float2bfloat16(f);
    return *reinterpret_cast<ushort*>(&h);
}
__device__ __forceinline__ uint pkbf(float re, float im) {
    return (uint)f2bf(re) | ((uint)f2bf(im) << 16);
}

__global__ void k_twiddle(float* ws) {
    const float TWO_PI = 6.28318530717958647692f;
    int t = threadIdx.x;
    ushort* Wfb = (ushort*)(ws + 13976);  // [2][80][64] bf16
    for (int e = t; e < 80 * 64; e += 256) {
        int k = e >> 6, r = e & 63;
        float vr = 0.f, vi = 0.f;
        if (k < 68) {
            int ph = (k * (r + 2)) % 68;
            float a = TWO_PI * (float)ph / 68.0f;
            vr = cosf(a); vi = -sinf(a);
        }
        Wfb[e]        = f2bf(vr);
        Wfb[5120 + e] = f2bf(vi);
    }
    ushort* Wib = (ushort*)(ws + 19096);  // [2][80][128] bf16 pre-swizzled
    for (int e = t; e < 80 * 96; e += 256) {
        int p = e / 96, k = e % 96;
        float vr = 0.f, vi = 0.f;
        if (p < 68 && k < 68) {
            int ph = (p * k) % 68;
            float a = TWO_PI * (float)ph / 68.0f;
            vr = cosf(a) / 68.0f; vi = sinf(a) / 68.0f;
        }
        int dst = p * 128 + (((k >> 3) ^ (p & 7)) << 3) + (k & 7);
        Wib[dst]         = f2bf(vr);
        Wib[10240 + dst] = f2bf(vi);
    }
    ushort* Wgb = (ushort*)(ws + 29336);  // [80][128] bf16 pre-swizzled
    for (int e = t; e < 80 * 96; e += 256) {
        int q = e / 96, k = e % 96;
        float v = 0.f;
        if (q < 68 && k < 70) {
            int k2 = (k < KH) ? k : (k - KH);
            int ph = (q * k2) % 68;
            float a = TWO_PI * (float)ph / 68.0f;
            float alpha = (k2 == 0 || k2 == 34) ? 1.0f : 2.0f;
            v = (k < KH) ? (alpha * cosf(a) / 68.0f)
                         : (-alpha * sinf(a) / 68.0f);
        }
        int dst = q * 128 + (((k >> 3) ^ (q & 7)) << 3) + (k & 7);
        Wgb[dst] = f2bf(v);
    }
}

// zero only the seam bands (rows/cols 66,67,132,133,198,199 of each image)
__global__ void k_zero_seams(float* out) {
    int b = blockIdx.x / 12, line = blockIdx.x % 12;
    const int seam[6] = {66, 67, 132, 133, 198, 199};
    int t = threadIdx.x;
    if (line < 6) {
        int y = seam[line];
        float4* dst = (float4*)(out + ((size_t)(b * 256 + y)) * 256 * 64);
        for (int e = t; e < 4096; e += 256) dst[e] = make_float4(0, 0, 0, 0);
    } else {
        int x = seam[line - 6];
        float4* dst = (float4*)out;
        for (int e = t; e < 4096; e += 256) {
            int y = e >> 4, f = e & 15;
            dst[(((size_t)(b * 256 + y)) * 256 + x) * 16 + f] = make_float4(0, 0, 0, 0);
        }
    }
}

// ---------- one-time: kernel spectrum -> Ktb bf16 [bin][plane][o][i_swz] ----
// Block = (k1-pair, o). Window = 2*68 = 136 floats (34 float4, exact tiling).
// LDS stride 137 floats (137 mod 32 = 9, gcd(9,32)=1 -> conflict-free reads).
__global__ __launch_bounds__(256) void k_kprep(
        const float* __restrict__ kr, const float* __restrict__ ki,
        ushort* __restrict__ Ktb) {
    __shared__ float sW[64 * 137];      // 35 KB
    int k1p = blockIdx.x >> 6, o = blockIdx.x & 63;
    int t = threadIdx.x;
    for (int ph = 0; ph < 2; ++ph) {
        const float* src = ph ? ki : kr;
        for (int e = t; e < 64 * 34; e += 256) {
            int ii = e / 34, f = e % 34;
            size_t g = (size_t)(o * 64 + ii) * 4624 + (size_t)k1p * 136 + f * 4;
            float4 v = *(const float4*)(src + g);
            float* d = sW + ii * 137 + f * 4;
            d[0] = v.x; d[1] = v.y; d[2] = v.z; d[3] = v.w;
        }
        __syncthreads();
        for (int e = t; e < 2 * KH * 64; e += 256) {
            int k1l = e / 2240;
            int rem = e % 2240;
            int k2 = rem >> 6, i = rem & 63;
            int sw = (((i >> 3) ^ (o & 7)) << 3) | (i & 7);
            size_t dst = ((size_t)((2 * k1p + k1l) * KH + k2)) * 8192
                         + (size_t)ph * 4096 + (size_t)o * 64 + sw;
            Ktb[dst] = f2bf(sW[i * 137 + k1l * 68 + k2]);
        }
        __syncthreads();
    }
}

// ---------------- stage 1: row DFT — bf16 MFMA ----------------
// Y[nl][k2][r][i] = sum_c x[b, tr*64+r, tc*64+c, i] * Wf[k2][c]
__global__ __launch_bounds__(512) void k_fwd_row(
        const float* __restrict__ x, const ushort* __restrict__ Wfb,
        uint* __restrict__ Y, int c0) {
    __shared__ __align__(16) ushort sAr[48 * 64];
    __shared__ __align__(16) ushort sAi[48 * 64];
    __shared__ __align__(16) ushort sB[4 * 64 * 64];
    int gid = blockIdx.x;
    int lc = gid >> 8;
    int rem = gid & 255;
    int nl = rem >> 4, rq = rem & 15;
    int n = (c0 + lc) * 16 + nl;
    int b = n >> 4, tr = (n >> 2) & 3, tc = n & 3;
    int t = threadIdx.x;
    for (int e = t; e < 3072; e += 512) {
        int m = e >> 6, c = e & 63;
        int sw = (m << 6) + (((c >> 3) ^ (m & 7)) << 3) + (c & 7);
        sAr[sw] = Wfb[e];
        sAi[sw] = Wfb[5120 + e];
    }
    for (int e = t; e < 4096; e += 512) {
        int rr = e >> 10, f = e & 1023;
        int c = f >> 4, i0 = (f & 15) << 2;
        int y = tr * 64 + rq * 4 + rr;
        const float4* src = (const float4*)(x + ((size_t)(b * 256 + y) * 256
                                                 + tc * 64) * 64 + (c << 6) + i0);
        float4 v = *src;
        float vv[4] = {v.x, v.y, v.z, v.w};
        #pragma unroll
        for (int u = 0; u < 4; ++u) {
            int i = i0 + u;
            sB[(rr << 12) + (i << 6) + (((c >> 3) ^ (i & 7)) << 3) + (c & 7)]
                = f2bf(vv[u]);
        }
    }
    __syncthreads();
    uint* Yc = Y + (size_t)lc * CHS;
    int lane = t & 63, w = t >> 6;
    int lm = lane & 15, kg = lane >> 4;
    int ba0 = ((kg ^ (lm & 7)) << 3);
    int ba1 = (((kg + 4) ^ (lm & 7)) << 3);
    for (int tid = w; tid < 48; tid += 8) {
        int rr = tid / 12, rem2 = tid % 12;
        int mt = rem2 >> 2, nt = rem2 & 3;
        int am = mt * 16 + lm, bn = nt * 16 + lm;
        s16x8 a0r = *(const s16x8*)(sAr + (am << 6) + ba0);
        s16x8 a1r = *(const s16x8*)(sAr + (am << 6) + ba1);
        s16x8 a0i = *(const s16x8*)(sAi + (am << 6) + ba0);
        s16x8 a1i = *(const s16x8*)(sAi + (am << 6) + ba1);
        s16x8 b0 = *(const s16x8*)(sB + (rr << 12) + (bn << 6) + ba0);
        s16x8 b1 = *(const s16x8*)(sB + (rr << 12) + (bn << 6) + ba1);
        f32x4 yr = {0.f, 0.f, 0.f, 0.f}, yi = yr;
        yr = __builtin_amdgcn_mfma_f32_16x16x32_bf16(a0r, b0, yr, 0, 0, 0);
        yr = __builtin_amdgcn_mfma_f32_16x16x32_bf16(a1r, b1, yr, 0, 0, 0);
        yi = __builtin_amdgcn_mfma_f32_16x16x32_bf16(a0i, b0, yi, 0, 0, 0);
        yi = __builtin_amdgcn_mfma_f32_16x16x32_bf16(a1i, b1, yi, 0, 0, 0);
        int r = rq * 4 + rr;
        #pragma unroll
        for (int g2 = 0; g2 < 4; ++g2) {
            int k2 = mt * 16 + kg * 4 + g2;
            if (k2 < KH)
                Yc[((size_t)(nl * KH + k2) * 64 + r) * 64 + nt * 16 + lm]
                    = pkbf(yr[g2], yi[g2]);
        }
    }
}

// ---------------- stage 2: column DFT — bf16 MFMA ----------------
// X[nl][k1][k2][i] = sum_r Wf[k1][r] * Y[nl][k2][r][i]
__global__ __launch_bounds__(512) void k_fwd_col(
        const uint* __restrict__ Y, const ushort* __restrict__ Wfb,
        uint* __restrict__ X) {
    __shared__ __align__(16) ushort sAr[80 * 64];
    __shared__ __align__(16) ushort sAi[80 * 64];
    __shared__ __align__(16) ushort sBr[64 * 64];
    __shared__ __align__(16) ushort sBi[64 * 64];
    int lc = blockIdx.x / 560;
    int rem = blockIdx.x % 560;
    int nl = rem / KH, k2 = rem % KH;
    const uint* Yg = Y + (size_t)lc * CHS + ((size_t)(nl * KH + k2)) * 4096;
    uint* Xc = X + (size_t)lc * CHS;
    int t = threadIdx.x;
    for (int e = t; e < 5120; e += 512) {
        int m = e >> 6, r = e & 63;
        int sw = (m << 6) + ((((r >> 3) ^ (m & 7))) << 3) + (r & 7);
        sAr[sw] = Wfb[e];
        sAi[sw] = Wfb[5120 + e];
    }
    for (int e = t; e < 4096; e += 512) {
        int i = e & 63, r = e >> 6;
        uint v = Yg[e];
        int sw = (i << 6) + ((((r >> 3) ^ (i & 7))) << 3) + (r & 7);
        sBr[sw] = (ushort)(v & 0xffff);
        sBi[sw] = (ushort)(v >> 16);
    }
    __syncthreads();
    int lane = t & 63, w = t >> 6;
    int lm = lane & 15, kg = lane >> 4;
    int ba0 = ((kg ^ (lm & 7)) << 3);
    int ba1 = (((kg + 4) ^ (lm & 7)) << 3);
    for (int tid = w; tid < 20; tid += 8) {
        int mt = tid >> 2, nt = tid & 3;
        int am = mt * 16 + lm, bn = nt * 16 + lm;
        s16x8 ar0 = *(const s16x8*)(sAr + (am << 6) + ba0);
        s16x8 ar1 = *(const s16x8*)(sAr + (am << 6) + ba1);
        s16x8 ai0 = *(const s16x8*)(sAi + (am << 6) + ba0);
        s16x8 ai1 = *(const s16x8*)(sAi + (am << 6) + ba1);
        s16x8 br0 = *(const s16x8*)(sBr + (bn << 6) + ba0);
        s16x8 br1 = *(const s16x8*)(sBr + (bn << 6) + ba1);
        s16x8 bi0 = *(const s16x8*)(sBi + (bn << 6) + ba0);
        s16x8 bi1 = *(const s16x8*)(sBi + (bn << 6) + ba1);
        f32x4 rr = {0.f, 0.f, 0.f, 0.f}, ii = rr, ri = rr, ir = rr;
        rr = __builtin_amdgcn_mfma_f32_16x16x32_bf16(ar0, br0, rr, 0, 0, 0);
        rr = __builtin_amdgcn_mfma_f32_16x16x32_bf16(ar1, br1, rr, 0, 0, 0);
        ii = __builtin_amdgcn_mfma_f32_16x16x32_bf16(ai0, bi0, ii, 0, 0, 0);
        ii = __builtin_amdgcn_mfma_f32_16x16x32_bf16(ai1, bi1, ii, 0, 0, 0);
        ri = __builtin_amdgcn_mfma_f32_16x16x32_bf16(ar0, bi0, ri, 0, 0, 0);
        ri = __builtin_amdgcn_mfma_f32_16x16x32_bf16(ar1, bi1, ri, 0, 0, 0);
        ir = __builtin_amdgcn_mfma_f32_16x16x32_bf16(ai0, br0, ir, 0, 0, 0);
        ir = __builtin_amdgcn_mfma_f32_16x16x32_bf16(ai1, br1, ir, 0, 0, 0);
        #pragma unroll
        for (int g2 = 0; g2 < 4; ++g2) {
            int k1 = mt * 16 + kg * 4 + g2;
            if (k1 < 68)
                Xc[((size_t)(nl * 68 + k1) * KH + k2) * 64 + nt * 16 + lm]
                    = pkbf(rr[g2] - ii[g2], ri[g2] + ir[g2]);
        }
    }
}

// ---------------- stage 3: channel mix — bf16 MFMA ----------------
// O[nl][k2][k1][o] = sum_i X[nl][k1][k2][i] * K[bin][i][o]
// Block = bin; Ktb staged ONCE in LDS, loop over all CH chunks.
__global__ __launch_bounds__(256) void k_mix(
        const uint* __restrict__ X, const ushort* __restrict__ Ktb,
        uint* __restrict__ O, int CH) {
    __shared__ __align__(16) ushort sAr[16 * 64];
    __shared__ __align__(16) ushort sAi[16 * 64];
    __shared__ __align__(16) ushort sB[2 * 64 * 64];
    int bin = blockIdx.x;
    int k1 = bin / KH, k2 = bin % KH;
    int t = threadIdx.x;
    const uint4* ksrc = (const uint4*)(Ktb + (size_t)bin * 8192);
    for (int e = t; e < 1024; e += 256) ((uint4*)sB)[e] = ksrc[e];
    const ushort* sBr = sB;
    const ushort* sBi = sB + 4096;
    int lane = t & 63, w = t >> 6;
    int lm = lane & 15, kg = lane >> 4;
    for (int lc = 0; lc < CH; ++lc) {
        const uint* Xc = X + (size_t)lc * CHS;
        uint* Oc = O + (size_t)lc * CHS;
        for (int e = t; e < 1024; e += 256) {
            int n = e >> 6, i = e & 63;
            uint v = Xc[((size_t)(n * 68 + k1) * KH + k2) * 64 + i];
            int sw = (n << 6) + (((i >> 3) ^ (n & 7)) << 3) + (i & 7);
            sAr[sw] = (ushort)(v & 0xffff);
            sAi[sw] = (ushort)(v >> 16);
        }
        __syncthreads();
        f32x4 rr = {0.f, 0.f, 0.f, 0.f}, ii = rr, ri = rr, ir = rr;
        #pragma unroll
        for (int st = 0; st < 2; ++st) {
            int blk = kg + st * 4;
            int ao = (lm << 6) + ((blk ^ (lm & 7)) << 3);
            int bo = ((w * 16 + lm) << 6) + ((blk ^ (lm & 7)) << 3);
            s16x8 axr = *(const s16x8*)(sAr + ao);
            s16x8 axi = *(const s16x8*)(sAi + ao);
            s16x8 bxr = *(const s16x8*)(sBr + bo);
            s16x8 bxi = *(const s16x8*)(sBi + bo);
            rr = __builtin_amdgcn_mfma_f32_16x16x32_bf16(axr, bxr, rr, 0, 0, 0);
            ii = __builtin_amdgcn_mfma_f32_16x16x32_bf16(axi, bxi, ii, 0, 0, 0);
            ri = __builtin_amdgcn_mfma_f32_16x16x32_bf16(axr, bxi, ri, 0, 0, 0);
            ir = __builtin_amdgcn_mfma_f32_16x16x32_bf16(axi, bxr, ir, 0, 0, 0);
        }
        #pragma unroll
        for (int g2 = 0; g2 < 4; ++g2) {
            int n = kg * 4 + g2;
            int o = w * 16 + lm;
            Oc[(((size_t)n * KH + k2) * 68 + k1) * 64 + o]
                = pkbf(rr[g2] - ii[g2], ri[g2] + ir[g2]);
        }
        __syncthreads();
    }
}

// ---------------- stage 4: inverse column DFT — bf16 MFMA ----------------
// Z[nl][p][k2][o] = sum_k1 Wi[p][k1] * O[nl][k2][k1][o]
__global__ __launch_bounds__(512) void k_inv_col(
        const uint* __restrict__ O, const ushort* __restrict__ Wib,
        uint* __restrict__ Z) {
    __shared__ __align__(16) ushort sAr[80 * 128];
    __shared__ __align__(16) ushort sAi[80 * 128];
    __shared__ __align__(16) ushort sBr[64 * 128];
    __shared__ __align__(16) ushort sBi[64 * 128];
    int lc = blockIdx.x / 560;
    int rem = blockIdx.x % 560;
    int nl = rem / KH, k2 = rem % KH;
    int t = threadIdx.x;
    const uint* Ob = O + (size_t)lc * CHS + ((size_t)nl * KH + k2) * 68 * 64;
    uint* Zc = Z + (size_t)lc * CHS;
    const uint4* wsrc = (const uint4*)Wib;
    for (int e = t; e < 1280; e += 512) ((uint4*)sAr)[e] = wsrc[e];
    for (int e = t; e < 1280; e += 512) ((uint4*)sAi)[e] = wsrc[1280 + e];
    uint4 zz = {0, 0, 0, 0};
    for (int e = t; e < 1024; e += 512) { ((uint4*)sBr)[e] = zz; ((uint4*)sBi)[e] = zz; }
    __syncthreads();
    for (int e = t; e < 4352; e += 512) {
        int k1 = e >> 6, o = e & 63;
        uint v = Ob[e];
        int sw = o * 128 + (((k1 >> 3) ^ (o & 7)) << 3) + (k1 & 7);
        sBr[sw] = (ushort)(v & 0xffff);
        sBi[sw] = (ushort)(v >> 16);
    }
    __syncthreads();
    int lane = t & 63, w = t >> 6;
    int lm = lane & 15, kg = lane >> 4;
    for (int tid = w; tid < 20; tid += 8) {
        int mt = tid >> 2, nt = tid & 3;
        int am = mt * 16 + lm, bn = nt * 16 + lm;
        f32x4 rr = {0.f, 0.f, 0.f, 0.f}, ii = rr, ri = rr, ir = rr;
        #pragma unroll
        for (int st = 0; st < 3; ++st) {
            int blk = kg + st * 4;
            int off = ((blk ^ (lm & 7)) << 3);
            s16x8 axr = *(const s16x8*)(sAr + am * 128 + off);
            s16x8 axi = *(const s16x8*)(sAi + am * 128 + off);
            s16x8 bxr = *(const s16x8*)(sBr + bn * 128 + off);
            s16x8 bxi = *(const s16x8*)(sBi + bn * 128 + off);
            rr = __builtin_amdgcn_mfma_f32_16x16x32_bf16(axr, bxr, rr, 0, 0, 0);
            ii = __builtin_amdgcn_mfma_f32_16x16x32_bf16(axi, bxi, ii, 0, 0, 0);
            ri = __builtin_amdgcn_mfma_f32_16x16x32_bf16(axr, bxi, ri, 0, 0, 0);
            ir = __builtin_amdgcn_mfma_f32_16x16x32_bf16(axi, bxr, ir, 0, 0, 0);
        }
        #pragma unroll
        for (int g2 = 0; g2 < 4; ++g2) {
            int p = mt * 16 + kg * 4 + g2;
            if (p < 68)
                Zc[(((size_t)(nl * 68 + p)) * KH + k2) * 64 + nt * 16 + lm]
                    = pkbf(rr[g2] - ii[g2], ri[g2] + ir[g2]);
        }
    }
}

// ---------------- stage 5: inverse row DFT + overlap-add — bf16 MFMA --------
// Block = (lc, nl, p-quad): Wgb staged once, 4 p-rows, double-buffered B.
__global__ __launch_bounds__(512) void k_fused_inv(
        const uint* __restrict__ Z, const ushort* __restrict__ Wgb,
        const float* __restrict__ bias, float* __restrict__ out, int c0) {
    __shared__ __align__(16) ushort sWg[80 * 128];      // 20 KB
    __shared__ __align__(16) ushort sBq[2][64 * 128];   // 32 KB
    int bid = blockIdx.x;
    int lc = bid / 272;
    int rem = bid % 272;
    int nl = rem / 17, pq = rem % 17;
    int b = c0 + lc;
    int tr = nl >> 2, tc = nl & 3;
    int t = threadIdx.x;
    const uint4* wsrc = (const uint4*)Wgb;
    for (int e = t; e < 1280; e += 512) ((uint4*)sWg)[e] = wsrc[e];
    uint4 zz = {0, 0, 0, 0};
    for (int e = t; e < 2048; e += 512) ((uint4*)sBq[0])[e] = zz;  // both bufs
    int lane = t & 63, w = t >> 6;
    int lm = lane & 15, kg = lane >> 4;
    float bv4[4];
    #pragma unroll
    for (int nt = 0; nt < 4; ++nt) bv4[nt] = bias[nt * 16 + lm];
    __syncthreads();
    for (int pp = 0; pp < 4; ++pp) {
        int p = pq * 4 + pp;
        int y = 66 * tr + p;
        if (y >= 256) break;            // block-uniform
        ushort* Bq = sBq[pp & 1];
        const uint* Zb = Z + (size_t)lc * CHS + ((size_t)(nl * 68 + p)) * KH * 64;
        for (int e = t; e < KH * 64; e += 512) {
            int k2 = e >> 6, o = e & 63;
            uint v = Zb[e];
            int kb = k2 + KH;
            Bq[o * 128 + (((k2 >> 3) ^ (o & 7)) << 3) + (k2 & 7)] = (ushort)(v & 0xffff);
            Bq[o * 128 + (((kb >> 3) ^ (o & 7)) << 3) + (kb & 7)] = (ushort)(v >> 16);
        }
        __syncthreads();
        bool rowu = !((p <= 1 && tr > 0) || (p >= 66 && tr < 3));
        float* orow = out + ((size_t)(b * 256 + y)) * 256 * 64;
        for (int tid = w; tid < 20; tid += 8) {
            int mt = tid >> 2, nt = tid & 3;
            int am = mt * 16 + lm, bn = nt * 16 + lm;
            f32x4 acc = {0.f, 0.f, 0.f, 0.f};
            #pragma unroll
            for (int st = 0; st < 3; ++st) {
                int blk = kg + st * 4;
                int off = ((blk ^ (lm & 7)) << 3);
                s16x8 av = *(const s16x8*)(sWg + am * 128 + off);
                s16x8 bv = *(const s16x8*)(Bq + bn * 128 + off);
                acc = __builtin_amdgcn_mfma_f32_16x16x32_bf16(av, bv, acc, 0, 0, 0);
            }
            int o = nt * 16 + lm;
            #pragma unroll
            for (int g2 = 0; g2 < 4; ++g2) {
                int q = mt * 16 + kg * 4 + g2;
                if (q >= 68) continue;
                int xx = 66 * tc + q;
                if (xx >= 256) continue;
                bool colu = !((q <= 1 && tc > 0) || (q >= 66 && tc < 3));
                float v = acc[g2] + bv4[nt];
                float* addr = orow + (size_t)xx * 64 + o;
                if (rowu && colu) *addr = v;
                else              atomicAdd(addr, v);
            }
        }
    }
}

extern "C" void kernel_launch(void* const* d_in, const int* in_sizes, int n_in,
                              void* d_out, int out_size, void* d_ws, size_t ws_size,
                              hipStream_t stream) {
    const float* x    = (const float*)d_in[0];
    const float* kr   = (const float*)d_in[1];
    const float* ki   = (const float*)d_in[2];
    const float* bias = (const float*)d_in[3];
    float* out = (float*)d_out;
    float* ws  = (float*)d_ws;

    int CH = 8;
    while (CH > 4 && (WS_HEAD + KTB_FLOATS + 2ull * CH * CHS) * 4ull > ws_size)
        CH >>= 1;

    ushort* Wfb  = (ushort*)(ws + 13976);
    ushort* Wib  = (ushort*)(ws + 19096);
    ushort* Wgb  = (ushort*)(ws + 29336);
    ushort* Ktb  = (ushort*)(ws + WS_HEAD);
    float*  bufA = ws + WS_HEAD + KTB_FLOATS;  // Y then O (as uint)
    float*  bufB = bufA + (size_t)CH * CHS;    // X then Z

    k_twiddle<<<1, 256, 0, stream>>>(ws);
    k_kprep<<<34 * 64, 256, 0, stream>>>(kr, ki, Ktb);
    k_zero_seams<<<96, 256, 0, stream>>>(out);

    for (int s = 0; s < 8; s += CH) {
        k_fwd_row<<<CH * 256, 512, 0, stream>>>(x, Wfb, (uint*)bufA, s);
        k_fwd_col<<<CH * 560, 512, 0, stream>>>((const uint*)bufA, Wfb, (uint*)bufB);
        k_mix<<<2380, 256, 0, stream>>>((const uint*)bufB, Ktb, (uint*)bufA, CH);
        k_inv_col<<<CH * 560, 512, 0, stream>>>((const uint*)bufA, Wib, (uint*)bufB);
        k_fused_inv<<<CH * 272, 512, 0, stream>>>((const uint*)bufB, Wgb, bias, out, s);
    }
}

// Round 26
// 365.491 us; speedup vs baseline: 1.0939x; 1.0177x over previous
//
#include <hip/hip_runtime.h>
#include <hip/hip_bf16.h>

// FFT-tiled conv: B=8, IMG=256, CIN=COUT=64, TILE=64, FFT=68, PAD=2.
// Frequency-domain per-tile conv via DFT-as-matmul, Hermitian half-spectrum
// (k2 in [0,35)), direct overlap-add (plain stores interior, atomics on seams,
// seam bands pre-zeroed). ALL five stages run on bf16 MFMA.
// ALL intermediates (Y,X,O,Z) stored as packed bf16 complex (uint re|im<<16).
// CH=4 keeps the inter-stage working set (~195 MB) inside the 256 MB L3.
//
// Layouts (per 16-tile chunk slot of CHS uints, oversized):
//   Y  [nl][k2][r][i]    uint   ((nl*35+k2)*64+r)*64 + i
//   X  [nl][k1][k2][i]   uint   ((nl*68+k1)*35+k2)*64 + i
//   O  [nl][k2][k1][o]   uint   ((nl*35+k2)*68+k1)*64 + o
//   Z  [nl][p][k2][o]    uint   ((nl*68+p)*35+k2)*64 + o
//   Ktb[bin][2][o][i] bf16 pre-swizzled, 39 MB one-time (bin = k1*35+k2)

#define KH   35
#define CHS  4874240ull                       // elements per chunk slot
#define KTB_FLOATS 9748480ull
#define WS_HEAD 34456ull

typedef float f32x4 __attribute__((ext_vector_type(4)));
typedef short s16x8 __attribute__((ext_vector_type(8)));

__device__ __forceinline__ ushort f2bf(float f) {
    __hip_bfloat16 h = __float2bfloat16(f);
    return *reinterpret_cast<ushort*>(&h);
}
__device__ __forceinline__ uint pkbf(float re, float im) {
    return (uint)f2bf(re) | ((uint)f2bf(im) << 16);
}

__global__ void k_twiddle(float* ws) {
    const float TWO_PI = 6.28318530717958647692f;
    int t = threadIdx.x;
    ushort* Wfb = (ushort*)(ws + 13976);  // [2][80][64] bf16
    for (int e = t; e < 80 * 64; e += 256) {
        int k = e >> 6, r = e & 63;
        float vr = 0.f, vi = 0.f;
        if (k < 68) {
            int ph = (k * (r + 2)) % 68;
            float a = TWO_PI * (float)ph / 68.0f;
            vr = cosf(a); vi = -sinf(a);
        }
        Wfb[e]        = f2bf(vr);
        Wfb[5120 + e] = f2bf(vi);
    }
    ushort* Wib = (ushort*)(ws + 19096);  // [2][80][128] bf16 pre-swizzled
    for (int e = t; e < 80 * 96; e += 256) {
        int p = e / 96, k = e % 96;
        float vr = 0.f, vi = 0.f;
        if (p < 68 && k < 68) {
            int ph = (p * k) % 68;
            float a = TWO_PI * (float)ph / 68.0f;
            vr = cosf(a) / 68.0f; vi = sinf(a) / 68.0f;
        }
        int dst = p * 128 + (((k >> 3) ^ (p & 7)) << 3) + (k & 7);
        Wib[dst]         = f2bf(vr);
        Wib[10240 + dst] = f2bf(vi);
    }
    ushort* Wgb = (ushort*)(ws + 29336);  // [80][128] bf16 pre-swizzled
    for (int e = t; e < 80 * 96; e += 256) {
        int q = e / 96, k = e % 96;
        float v = 0.f;
        if (q < 68 && k < 70) {
            int k2 = (k < KH) ? k : (k - KH);
            int ph = (q * k2) % 68;
            float a = TWO_PI * (float)ph / 68.0f;
            float alpha = (k2 == 0 || k2 == 34) ? 1.0f : 2.0f;
            v = (k < KH) ? (alpha * cosf(a) / 68.0f)
                         : (-alpha * sinf(a) / 68.0f);
        }
        int dst = q * 128 + (((k >> 3) ^ (q & 7)) << 3) + (k & 7);
        Wgb[dst] = f2bf(v);
    }
}

// zero only the seam bands (rows/cols 66,67,132,133,198,199 of each image)
__global__ void k_zero_seams(float* out) {
    int b = blockIdx.x / 12, line = blockIdx.x % 12;
    const int seam[6] = {66, 67, 132, 133, 198, 199};
    int t = threadIdx.x;
    if (line < 6) {
        int y = seam[line];
        float4* dst = (float4*)(out + ((size_t)(b * 256 + y)) * 256 * 64);
        for (int e = t; e < 4096; e += 256) dst[e] = make_float4(0, 0, 0, 0);
    } else {
        int x = seam[line - 6];
        float4* dst = (float4*)out;
        for (int e = t; e < 4096; e += 256) {
            int y = e >> 4, f = e & 15;
            dst[(((size_t)(b * 256 + y)) * 256 + x) * 16 + f] = make_float4(0, 0, 0, 0);
        }
    }
}

// ---------- one-time: kernel spectrum -> Ktb bf16 [bin][plane][o][i_swz] ----
// Block = (k1-pair, o). ALL kr+ki window loads issued up-front into registers
// (18 float4/thread in flight), then two LDS phases (stride 137: conflict-free).
__global__ __launch_bounds__(256) void k_kprep(
        const float* __restrict__ kr, const float* __restrict__ ki,
        ushort* __restrict__ Ktb) {
    __shared__ float sW[64 * 137];      // 35 KB
    int k1p = blockIdx.x >> 6, o = blockIdx.x & 63;
    int t = threadIdx.x;
    f32x4 vr[9], vi[9];
    #pragma unroll
    for (int j = 0; j < 9; ++j) {
        int e = t + j * 256;
        if (e < 2176) {
            int ii = e / 34, f = e % 34;
            size_t g = (size_t)(o * 64 + ii) * 4624 + (size_t)k1p * 136 + f * 4;
            vr[j] = *(const f32x4*)(kr + g);
            vi[j] = *(const f32x4*)(ki + g);
        }
    }
    #pragma unroll
    for (int j = 0; j < 9; ++j) {
        int e = t + j * 256;
        if (e < 2176) {
            int ii = e / 34, f = e % 34;
            float* d = sW + ii * 137 + f * 4;
            d[0] = vr[j][0]; d[1] = vr[j][1]; d[2] = vr[j][2]; d[3] = vr[j][3];
        }
    }
    __syncthreads();
    for (int e = t; e < 2 * KH * 64; e += 256) {
        int k1l = e / 2240, rem = e % 2240;
        int k2 = rem >> 6, i = rem & 63;
        int sw = (((i >> 3) ^ (o & 7)) << 3) | (i & 7);
        size_t dst = ((size_t)((2 * k1p + k1l) * KH + k2)) * 8192
                     + (size_t)o * 64 + sw;
        Ktb[dst] = f2bf(sW[i * 137 + k1l * 68 + k2]);
    }
    __syncthreads();
    #pragma unroll
    for (int j = 0; j < 9; ++j) {
        int e = t + j * 256;
        if (e < 2176) {
            int ii = e / 34, f = e % 34;
            float* d = sW + ii * 137 + f * 4;
            d[0] = vi[j][0]; d[1] = vi[j][1]; d[2] = vi[j][2]; d[3] = vi[j][3];
        }
    }
    __syncthreads();
    for (int e = t; e < 2 * KH * 64; e += 256) {
        int k1l = e / 2240, rem = e % 2240;
        int k2 = rem >> 6, i = rem & 63;
        int sw = (((i >> 3) ^ (o & 7)) << 3) | (i & 7);
        size_t dst = ((size_t)((2 * k1p + k1l) * KH + k2)) * 8192
                     + 4096 + (size_t)o * 64 + sw;
        Ktb[dst] = f2bf(sW[i * 137 + k1l * 68 + k2]);
    }
}

// ---------------- stage 1: row DFT — bf16 MFMA ----------------
// Y[nl][k2][r][i] = sum_c x[b, tr*64+r, tc*64+c, i] * Wf[k2][c]
__global__ __launch_bounds__(512) void k_fwd_row(
        const float* __restrict__ x, const ushort* __restrict__ Wfb,
        uint* __restrict__ Y, int c0) {
    __shared__ __align__(16) ushort sAr[48 * 64];
    __shared__ __align__(16) ushort sAi[48 * 64];
    __shared__ __align__(16) ushort sB[4 * 64 * 64];
    int gid = blockIdx.x;
    int lc = gid >> 8;
    int rem = gid & 255;
    int nl = rem >> 4, rq = rem & 15;
    int n = (c0 + lc) * 16 + nl;
    int b = n >> 4, tr = (n >> 2) & 3, tc = n & 3;
    int t = threadIdx.x;
    for (int e = t; e < 3072; e += 512) {
        int m = e >> 6, c = e & 63;
        int sw = (m << 6) + (((c >> 3) ^ (m & 7)) << 3) + (c & 7);
        sAr[sw] = Wfb[e];
        sAi[sw] = Wfb[5120 + e];
    }
    for (int e = t; e < 4096; e += 512) {
        int rr = e >> 10, f = e & 1023;
        int c = f >> 4, i0 = (f & 15) << 2;
        int y = tr * 64 + rq * 4 + rr;
        const float4* src = (const float4*)(x + ((size_t)(b * 256 + y) * 256
                                                 + tc * 64) * 64 + (c << 6) + i0);
        float4 v = *src;
        float vv[4] = {v.x, v.y, v.z, v.w};
        #pragma unroll
        for (int u = 0; u < 4; ++u) {
            int i = i0 + u;
            sB[(rr << 12) + (i << 6) + (((c >> 3) ^ (i & 7)) << 3) + (c & 7)]
                = f2bf(vv[u]);
        }
    }
    __syncthreads();
    uint* Yc = Y + (size_t)lc * CHS;
    int lane = t & 63, w = t >> 6;
    int lm = lane & 15, kg = lane >> 4;
    int ba0 = ((kg ^ (lm & 7)) << 3);
    int ba1 = (((kg + 4) ^ (lm & 7)) << 3);
    for (int tid = w; tid < 48; tid += 8) {
        int rr = tid / 12, rem2 = tid % 12;
        int mt = rem2 >> 2, nt = rem2 & 3;
        int am = mt * 16 + lm, bn = nt * 16 + lm;
        s16x8 a0r = *(const s16x8*)(sAr + (am << 6) + ba0);
        s16x8 a1r = *(const s16x8*)(sAr + (am << 6) + ba1);
        s16x8 a0i = *(const s16x8*)(sAi + (am << 6) + ba0);
        s16x8 a1i = *(const s16x8*)(sAi + (am << 6) + ba1);
        s16x8 b0 = *(const s16x8*)(sB + (rr << 12) + (bn << 6) + ba0);
        s16x8 b1 = *(const s16x8*)(sB + (rr << 12) + (bn << 6) + ba1);
        f32x4 yr = {0.f, 0.f, 0.f, 0.f}, yi = yr;
        yr = __builtin_amdgcn_mfma_f32_16x16x32_bf16(a0r, b0, yr, 0, 0, 0);
        yr = __builtin_amdgcn_mfma_f32_16x16x32_bf16(a1r, b1, yr, 0, 0, 0);
        yi = __builtin_amdgcn_mfma_f32_16x16x32_bf16(a0i, b0, yi, 0, 0, 0);
        yi = __builtin_amdgcn_mfma_f32_16x16x32_bf16(a1i, b1, yi, 0, 0, 0);
        int r = rq * 4 + rr;
        #pragma unroll
        for (int g2 = 0; g2 < 4; ++g2) {
            int k2 = mt * 16 + kg * 4 + g2;
            if (k2 < KH)
                Yc[((size_t)(nl * KH + k2) * 64 + r) * 64 + nt * 16 + lm]
                    = pkbf(yr[g2], yi[g2]);
        }
    }
}

// ---------------- stage 2: column DFT — bf16 MFMA ----------------
// X[nl][k1][k2][i] = sum_r Wf[k1][r] * Y[nl][k2][r][i]
__global__ __launch_bounds__(512) void k_fwd_col(
        const uint* __restrict__ Y, const ushort* __restrict__ Wfb,
        uint* __restrict__ X) {
    __shared__ __align__(16) ushort sAr[80 * 64];
    __shared__ __align__(16) ushort sAi[80 * 64];
    __shared__ __align__(16) ushort sBr[64 * 64];
    __shared__ __align__(16) ushort sBi[64 * 64];
    int lc = blockIdx.x / 560;
    int rem = blockIdx.x % 560;
    int nl = rem / KH, k2 = rem % KH;
    const uint* Yg = Y + (size_t)lc * CHS + ((size_t)(nl * KH + k2)) * 4096;
    uint* Xc = X + (size_t)lc * CHS;
    int t = threadIdx.x;
    for (int e = t; e < 5120; e += 512) {
        int m = e >> 6, r = e & 63;
        int sw = (m << 6) + ((((r >> 3) ^ (m & 7))) << 3) + (r & 7);
        sAr[sw] = Wfb[e];
        sAi[sw] = Wfb[5120 + e];
    }
    for (int e = t; e < 4096; e += 512) {
        int i = e & 63, r = e >> 6;
        uint v = Yg[e];
        int sw = (i << 6) + ((((r >> 3) ^ (i & 7))) << 3) + (r & 7);
        sBr[sw] = (ushort)(v & 0xffff);
        sBi[sw] = (ushort)(v >> 16);
    }
    __syncthreads();
    int lane = t & 63, w = t >> 6;
    int lm = lane & 15, kg = lane >> 4;
    int ba0 = ((kg ^ (lm & 7)) << 3);
    int ba1 = (((kg + 4) ^ (lm & 7)) << 3);
    for (int tid = w; tid < 20; tid += 8) {
        int mt = tid >> 2, nt = tid & 3;
        int am = mt * 16 + lm, bn = nt * 16 + lm;
        s16x8 ar0 = *(const s16x8*)(sAr + (am << 6) + ba0);
        s16x8 ar1 = *(const s16x8*)(sAr + (am << 6) + ba1);
        s16x8 ai0 = *(const s16x8*)(sAi + (am << 6) + ba0);
        s16x8 ai1 = *(const s16x8*)(sAi + (am << 6) + ba1);
        s16x8 br0 = *(const s16x8*)(sBr + (bn << 6) + ba0);
        s16x8 br1 = *(const s16x8*)(sBr + (bn << 6) + ba1);
        s16x8 bi0 = *(const s16x8*)(sBi + (bn << 6) + ba0);
        s16x8 bi1 = *(const s16x8*)(sBi + (bn << 6) + ba1);
        f32x4 rr = {0.f, 0.f, 0.f, 0.f}, ii = rr, ri = rr, ir = rr;
        rr = __builtin_amdgcn_mfma_f32_16x16x32_bf16(ar0, br0, rr, 0, 0, 0);
        rr = __builtin_amdgcn_mfma_f32_16x16x32_bf16(ar1, br1, rr, 0, 0, 0);
        ii = __builtin_amdgcn_mfma_f32_16x16x32_bf16(ai0, bi0, ii, 0, 0, 0);
        ii = __builtin_amdgcn_mfma_f32_16x16x32_bf16(ai1, bi1, ii, 0, 0, 0);
        ri = __builtin_amdgcn_mfma_f32_16x16x32_bf16(ar0, bi0, ri, 0, 0, 0);
        ri = __builtin_amdgcn_mfma_f32_16x16x32_bf16(ar1, bi1, ri, 0, 0, 0);
        ir = __builtin_amdgcn_mfma_f32_16x16x32_bf16(ai0, br0, ir, 0, 0, 0);
        ir = __builtin_amdgcn_mfma_f32_16x16x32_bf16(ai1, br1, ir, 0, 0, 0);
        #pragma unroll
        for (int g2 = 0; g2 < 4; ++g2) {
            int k1 = mt * 16 + kg * 4 + g2;
            if (k1 < 68)
                Xc[((size_t)(nl * 68 + k1) * KH + k2) * 64 + nt * 16 + lm]
                    = pkbf(rr[g2] - ii[g2], ri[g2] + ir[g2]);
        }
    }
}

// ---------------- stage 3: channel mix — bf16 MFMA ----------------
// O[nl][k2][k1][o] = sum_i X[nl][k1][k2][i] * K[bin][i][o]
__global__ __launch_bounds__(256) void k_mix(
        const uint* __restrict__ X, const ushort* __restrict__ Ktb,
        uint* __restrict__ O, int CH) {
    __shared__ __align__(16) ushort sAr[16 * 64];
    __shared__ __align__(16) ushort sAi[16 * 64];
    __shared__ __align__(16) ushort sB[2 * 64 * 64];
    int bin = blockIdx.x;
    int k1 = bin / KH, k2 = bin % KH;
    int t = threadIdx.x;
    const uint4* ksrc = (const uint4*)(Ktb + (size_t)bin * 8192);
    for (int e = t; e < 1024; e += 256) ((uint4*)sB)[e] = ksrc[e];
    const ushort* sBr = sB;
    const ushort* sBi = sB + 4096;
    int lane = t & 63, w = t >> 6;
    int lm = lane & 15, kg = lane >> 4;
    for (int lc = 0; lc < CH; ++lc) {
        const uint* Xc = X + (size_t)lc * CHS;
        uint* Oc = O + (size_t)lc * CHS;
        for (int e = t; e < 1024; e += 256) {
            int n = e >> 6, i = e & 63;
            uint v = Xc[((size_t)(n * 68 + k1) * KH + k2) * 64 + i];
            int sw = (n << 6) + (((i >> 3) ^ (n & 7)) << 3) + (i & 7);
            sAr[sw] = (ushort)(v & 0xffff);
            sAi[sw] = (ushort)(v >> 16);
        }
        __syncthreads();
        f32x4 rr = {0.f, 0.f, 0.f, 0.f}, ii = rr, ri = rr, ir = rr;
        #pragma unroll
        for (int st = 0; st < 2; ++st) {
            int blk = kg + st * 4;
            int ao = (lm << 6) + ((blk ^ (lm & 7)) << 3);
            int bo = ((w * 16 + lm) << 6) + ((blk ^ (lm & 7)) << 3);
            s16x8 axr = *(const s16x8*)(sAr + ao);
            s16x8 axi = *(const s16x8*)(sAi + ao);
            s16x8 bxr = *(const s16x8*)(sBr + bo);
            s16x8 bxi = *(const s16x8*)(sBi + bo);
            rr = __builtin_amdgcn_mfma_f32_16x16x32_bf16(axr, bxr, rr, 0, 0, 0);
            ii = __builtin_amdgcn_mfma_f32_16x16x32_bf16(axi, bxi, ii, 0, 0, 0);
            ri = __builtin_amdgcn_mfma_f32_16x16x32_bf16(axr, bxi, ri, 0, 0, 0);
            ir = __builtin_amdgcn_mfma_f32_16x16x32_bf16(axi, bxr, ir, 0, 0, 0);
        }
        #pragma unroll
        for (int g2 = 0; g2 < 4; ++g2) {
            int n = kg * 4 + g2;
            int o = w * 16 + lm;
            Oc[(((size_t)n * KH + k2) * 68 + k1) * 64 + o]
                = pkbf(rr[g2] - ii[g2], ri[g2] + ir[g2]);
        }
        __syncthreads();
    }
}

// ---------------- stage 4: inverse column DFT — bf16 MFMA ----------------
// Z[nl][p][k2][o] = sum_k1 Wi[p][k1] * O[nl][k2][k1][o]
__global__ __launch_bounds__(512) void k_inv_col(
        const uint* __restrict__ O, const ushort* __restrict__ Wib,
        uint* __restrict__ Z) {
    __shared__ __align__(16) ushort sAr[80 * 128];
    __shared__ __align__(16) ushort sAi[80 * 128];
    __shared__ __align__(16) ushort sBr[64 * 128];
    __shared__ __align__(16) ushort sBi[64 * 128];
    int lc = blockIdx.x / 560;
    int rem = blockIdx.x % 560;
    int nl = rem / KH, k2 = rem % KH;
    int t = threadIdx.x;
    const uint* Ob = O + (size_t)lc * CHS + ((size_t)nl * KH + k2) * 68 * 64;
    uint* Zc = Z + (size_t)lc * CHS;
    const uint4* wsrc = (const uint4*)Wib;
    for (int e = t; e < 1280; e += 512) ((uint4*)sAr)[e] = wsrc[e];
    for (int e = t; e < 1280; e += 512) ((uint4*)sAi)[e] = wsrc[1280 + e];
    uint4 zz = {0, 0, 0, 0};
    for (int e = t; e < 1024; e += 512) { ((uint4*)sBr)[e] = zz; ((uint4*)sBi)[e] = zz; }
    __syncthreads();
    for (int e = t; e < 4352; e += 512) {
        int k1 = e >> 6, o = e & 63;
        uint v = Ob[e];
        int sw = o * 128 + (((k1 >> 3) ^ (o & 7)) << 3) + (k1 & 7);
        sBr[sw] = (ushort)(v & 0xffff);
        sBi[sw] = (ushort)(v >> 16);
    }
    __syncthreads();
    int lane = t & 63, w = t >> 6;
    int lm = lane & 15, kg = lane >> 4;
    for (int tid = w; tid < 20; tid += 8) {
        int mt = tid >> 2, nt = tid & 3;
        int am = mt * 16 + lm, bn = nt * 16 + lm;
        f32x4 rr = {0.f, 0.f, 0.f, 0.f}, ii = rr, ri = rr, ir = rr;
        #pragma unroll
        for (int st = 0; st < 3; ++st) {
            int blk = kg + st * 4;
            int off = ((blk ^ (lm & 7)) << 3);
            s16x8 axr = *(const s16x8*)(sAr + am * 128 + off);
            s16x8 axi = *(const s16x8*)(sAi + am * 128 + off);
            s16x8 bxr = *(const s16x8*)(sBr + bn * 128 + off);
            s16x8 bxi = *(const s16x8*)(sBi + bn * 128 + off);
            rr = __builtin_amdgcn_mfma_f32_16x16x32_bf16(axr, bxr, rr, 0, 0, 0);
            ii = __builtin_amdgcn_mfma_f32_16x16x32_bf16(axi, bxi, ii, 0, 0, 0);
            ri = __builtin_amdgcn_mfma_f32_16x16x32_bf16(axr, bxi, ri, 0, 0, 0);
            ir = __builtin_amdgcn_mfma_f32_16x16x32_bf16(axi, bxr, ir, 0, 0, 0);
        }
        #pragma unroll
        for (int g2 = 0; g2 < 4; ++g2) {
            int p = mt * 16 + kg * 4 + g2;
            if (p < 68)
                Zc[(((size_t)(nl * 68 + p)) * KH + k2) * 64 + nt * 16 + lm]
                    = pkbf(rr[g2] - ii[g2], ri[g2] + ir[g2]);
        }
    }
}

// ---------------- stage 5: inverse row DFT + overlap-add — bf16 MFMA --------
// Block = (lc, nl, p-quad): Wgb staged once, 4 p-rows, double-buffered B.
__global__ __launch_bounds__(512) void k_fused_inv(
        const uint* __restrict__ Z, const ushort* __restrict__ Wgb,
        const float* __restrict__ bias, float* __restrict__ out, int c0) {
    __shared__ __align__(16) ushort sWg[80 * 128];      // 20 KB
    __shared__ __align__(16) ushort sBq[2][64 * 128];   // 32 KB
    int bid = blockIdx.x;
    int lc = bid / 272;
    int rem = bid % 272;
    int nl = rem / 17, pq = rem % 17;
    int b = c0 + lc;
    int tr = nl >> 2, tc = nl & 3;
    int t = threadIdx.x;
    const uint4* wsrc = (const uint4*)Wgb;
    for (int e = t; e < 1280; e += 512) ((uint4*)sWg)[e] = wsrc[e];
    uint4 zz = {0, 0, 0, 0};
    for (int e = t; e < 2048; e += 512) ((uint4*)sBq[0])[e] = zz;  // both bufs
    int lane = t & 63, w = t >> 6;
    int lm = lane & 15, kg = lane >> 4;
    float bv4[4];
    #pragma unroll
    for (int nt = 0; nt < 4; ++nt) bv4[nt] = bias[nt * 16 + lm];
    __syncthreads();
    for (int pp = 0; pp < 4; ++pp) {
        int p = pq * 4 + pp;
        int y = 66 * tr + p;
        if (y >= 256) break;            // block-uniform
        ushort* Bq = sBq[pp & 1];
        const uint* Zb = Z + (size_t)lc * CHS + ((size_t)(nl * 68 + p)) * KH * 64;
        for (int e = t; e < KH * 64; e += 512) {
            int k2 = e >> 6, o = e & 63;
            uint v = Zb[e];
            int kb = k2 + KH;
            Bq[o * 128 + (((k2 >> 3) ^ (o & 7)) << 3) + (k2 & 7)] = (ushort)(v & 0xffff);
            Bq[o * 128 + (((kb >> 3) ^ (o & 7)) << 3) + (kb & 7)] = (ushort)(v >> 16);
        }
        __syncthreads();
        bool rowu = !((p <= 1 && tr > 0) || (p >= 66 && tr < 3));
        float* orow = out + ((size_t)(b * 256 + y)) * 256 * 64;
        for (int tid = w; tid < 20; tid += 8) {
            int mt = tid >> 2, nt = tid & 3;
            int am = mt * 16 + lm, bn = nt * 16 + lm;
            f32x4 acc = {0.f, 0.f, 0.f, 0.f};
            #pragma unroll
            for (int st = 0; st < 3; ++st) {
                int blk = kg + st * 4;
                int off = ((blk ^ (lm & 7)) << 3);
                s16x8 av = *(const s16x8*)(sWg + am * 128 + off);
                s16x8 bv = *(const s16x8*)(Bq + bn * 128 + off);
                acc = __builtin_amdgcn_mfma_f32_16x16x32_bf16(av, bv, acc, 0, 0, 0);
            }
            int o = nt * 16 + lm;
            #pragma unroll
            for (int g2 = 0; g2 < 4; ++g2) {
                int q = mt * 16 + kg * 4 + g2;
                if (q >= 68) continue;
                int xx = 66 * tc + q;
                if (xx >= 256) continue;
                bool colu = !((q <= 1 && tc > 0) || (q >= 66 && tc < 3));
                float v = acc[g2] + bv4[nt];
                float* addr = orow + (size_t)xx * 64 + o;
                if (rowu && colu) *addr = v;
                else              atomicAdd(addr, v);
            }
        }
    }
}

extern "C" void kernel_launch(void* const* d_in, const int* in_sizes, int n_in,
                              void* d_out, int out_size, void* d_ws, size_t ws_size,
                              hipStream_t stream) {
    const float* x    = (const float*)d_in[0];
    const float* kr   = (const float*)d_in[1];
    const float* ki   = (const float*)d_in[2];
    const float* bias = (const float*)d_in[3];
    float* out = (float*)d_out;
    float* ws  = (float*)d_ws;

    int CH = 4;   // working set bufA+bufB ~156 MB + Ktb 39 -> L3-resident
    while (CH > 1 && (WS_HEAD + KTB_FLOATS + 2ull * CH * CHS) * 4ull > ws_size)
        CH >>= 1;

    ushort* Wfb  = (ushort*)(ws + 13976);
    ushort* Wib  = (ushort*)(ws + 19096);
    ushort* Wgb  = (ushort*)(ws + 29336);
    ushort* Ktb  = (ushort*)(ws + WS_HEAD);
    float*  bufA = ws + WS_HEAD + KTB_FLOATS;  // Y then O (as uint)
    float*  bufB = bufA + (size_t)CH * CHS;    // X then Z

    k_twiddle<<<1, 256, 0, stream>>>(ws);
    k_kprep<<<34 * 64, 256, 0, stream>>>(kr, ki, Ktb);
    k_zero_seams<<<96, 256, 0, stream>>>(out);

    for (int s = 0; s < 8; s += CH) {
        k_fwd_row<<<CH * 256, 512, 0, stream>>>(x, Wfb, (uint*)bufA, s);
        k_fwd_col<<<CH * 560, 512, 0, stream>>>((const uint*)bufA, Wfb, (uint*)bufB);
        k_mix<<<2380, 256, 0, stream>>>((const uint*)bufB, Ktb, (uint*)bufA, CH);
        k_inv_col<<<CH * 560, 512, 0, stream>>>((const uint*)bufA, Wib, (uint*)bufB);
        k_fused_inv<<<CH * 272, 512, 0, stream>>>((const uint*)bufB, Wgb, bias, out, s);
    }
}